// Round 3
// baseline (178.662 us; speedup 1.0000x reference)
//
#include <hip/hip_runtime.h>

#define WI 512
#define HI 512
#define WO 2048
#define HO 2048
#define NIMG 8
#define CCH 3
#define EPS 1e-8f
#define ROWS 4
#define PLANE (HI * WI)          // 262144 texels per src plane

// ===========================================================================
// Table kernel: per (image, output coord) 1-D bilinear entry {w0,w1,off0,off1}
// for both axes. Weights premultiplied by validity (zeros padding); y offsets
// premultiplied by WI so offset arithmetic in the main kernel is one add.
// ===========================================================================
__global__ void diffcomp_tables(const float* __restrict__ coor,
                                int4* __restrict__ xtab,
                                int4* __restrict__ ytab) {
    const int idx = blockIdx.x * 256 + threadIdx.x;    // [0, 2*NIMG*2048)
    const bool isY = idx >= NIMG * WO;
    const int rem = isY ? idx - NIMG * WO : idx;
    const int n   = rem >> 11;
    const int pos = rem & 2047;

    const float cx = coor[n * 4 + 0];
    const float cy = coor[n * 4 + 1];
    const float cw = coor[n * 4 + 2];
    const float ch = coor[n * 4 + 3];

    float a, t, INF;
    if (!isY) {
        const float x = (1.0f / (1.0f + expf(-cx))) * (float)WO;
        const float w = (1.0f / (1.0f + expf(-cw))) * (float)WO;
        a = (float)WO / (w + EPS);
        t = (2.0f / (float)WO) * ((float)WO * 0.5f - x) * a;
        INF = (float)WI;
    } else {
        const float y = (1.0f / (1.0f + expf(-cy))) * (float)HO;
        const float h = (1.0f / (1.0f + expf(-ch))) * (float)HO;
        a = (float)HO / (h + EPS);
        t = (2.0f / (float)HO) * ((float)HO * 0.5f - y) * a;
        INF = (float)HI;
    }

    const float s  = (2.0f * (float)pos + 1.0f) / 2048.0f - 1.0f;
    const float g  = a * s + t;
    const float ic = ((g + 1.0f) * INF - 1.0f) * 0.5f;
    const float f0 = floorf(ic);
    const float fr1 = ic - f0;
    const float fr0 = 1.0f - fr1;
    const float f1 = f0 + 1.0f;
    const float v0 = (f0 >= 0.0f && f0 < INF) ? 1.0f : 0.0f;
    const float v1 = (f1 >= 0.0f && f1 < INF) ? 1.0f : 0.0f;
    const float w0 = fr0 * v0;
    const float w1 = fr1 * v1;
    int c0 = (int)fminf(fmaxf(f0, 0.0f), INF - 1.0f);
    int c1 = (int)fminf(fmaxf(f1, 0.0f), INF - 1.0f);
    if (isY) { c0 *= WI; c1 *= WI; }

    int4 e;
    e.x = __float_as_int(w0);
    e.y = __float_as_int(w1);
    e.z = c0;
    e.w = c1;
    (isY ? ytab : xtab)[(n << 11) + pos] = e;
}

// ===========================================================================
// Transpose kernel: src [N,C,HI,WI] planar -> srcI [N,HI*WI] float4 (rgb0).
// Fully coalesced both sides; ~25 MB read + 33 MB write, one-shot.
// ===========================================================================
__launch_bounds__(256)
__global__ void diffcomp_interleave(const float* __restrict__ src,
                                    float4* __restrict__ srcI) {
    const int idx = blockIdx.x * 256 + threadIdx.x;    // [0, NIMG*PLANE)
    const int n   = idx >> 18;                         // / PLANE
    const int rem = idx & (PLANE - 1);
    const float* p = src + n * (CCH * PLANE) + rem;
    float4 v;
    v.x = p[0 * PLANE];
    v.y = p[1 * PLANE];
    v.z = p[2 * PLANE];
    v.w = 0.0f;
    srcI[idx] = v;
}

// ===========================================================================
// Main kernel v3: tile = 256 wo x ROWS ho, one thread per column.
// X entries in registers (8 coalesced int4), y entries broadcast from LDS.
// Per covered image: 4 float4 gathers (all channels in one load).
// Mask==0 images skipped (bit-exact: bg*(1-0)+s*0 == bg).
// ===========================================================================
__launch_bounds__(256)
__global__ void diffcomp_main3(const float4* __restrict__ srcI,
                               const float* __restrict__ bg,
                               const int4* __restrict__ xtab,
                               const int4* __restrict__ ytab,
                               float* __restrict__ out) {
    __shared__ int4 ylds[ROWS * NIMG];

    const int tid = threadIdx.x;
    const int wo  = blockIdx.x * 256 + tid;
    const int ho0 = blockIdx.y * ROWS;

    if (tid < ROWS * NIMG) {
        const int r = tid >> 3;
        const int n = tid & 7;
        ylds[tid] = ytab[(n << 11) + ho0 + r];
    }

    float wx0[NIMG], wx1[NIMG], mxv[NIMG];
    int   ox0[NIMG], ox1[NIMG];
#pragma unroll
    for (int n = 0; n < NIMG; n++) {
        const int4 e = xtab[(n << 11) + wo];
        wx0[n] = __int_as_float(e.x);
        wx1[n] = __int_as_float(e.y);
        ox0[n] = e.z;
        ox1[n] = e.w;
        mxv[n] = wx0[n] + wx1[n];
    }

    __syncthreads();

    for (int r = 0; r < ROWS; r++) {
        const int ho  = ho0 + r;
        const int pix = ho * WO + wo;

        float acc0 = bg[0 * HO * WO + pix];
        float acc1 = bg[1 * HO * WO + pix];
        float acc2 = bg[2 * HO * WO + pix];

#pragma unroll
        for (int n = 0; n < NIMG; n++) {
            const int4 ey = ylds[r * NIMG + n];
            const float wy0 = __int_as_float(ey.x);
            const float wy1 = __int_as_float(ey.y);
            const float m = (wy0 + wy1) * mxv[n];
            if (m > 0.0f) {
                const float4* p = srcI + (n << 18);
                const float4 v00 = p[ey.z + ox0[n]];
                const float4 v01 = p[ey.z + ox1[n]];
                const float4 v10 = p[ey.w + ox0[n]];
                const float4 v11 = p[ey.w + ox1[n]];
                const float om = 1.0f - m;
                const float s0 = (v00.x * wy0 + v10.x * wy1) * wx0[n]
                               + (v01.x * wy0 + v11.x * wy1) * wx1[n];
                const float s1 = (v00.y * wy0 + v10.y * wy1) * wx0[n]
                               + (v01.y * wy0 + v11.y * wy1) * wx1[n];
                const float s2 = (v00.z * wy0 + v10.z * wy1) * wx0[n]
                               + (v01.z * wy0 + v11.z * wy1) * wx1[n];
                acc0 = acc0 * om + s0 * m;
                acc1 = acc1 * om + s1 * m;
                acc2 = acc2 * om + s2 * m;
            }
        }

        out[0 * HO * WO + pix] = acc0;
        out[1 * HO * WO + pix] = acc1;
        out[2 * HO * WO + pix] = acc2;
    }
}

// ===========================================================================
// Fallback main (round-2 table version, planar src) if ws can't hold srcI.
// ===========================================================================
__launch_bounds__(256)
__global__ void diffcomp_main2(const float* __restrict__ src,
                               const float* __restrict__ bg,
                               const int4* __restrict__ xtab,
                               const int4* __restrict__ ytab,
                               float* __restrict__ out) {
    __shared__ int4 ylds[ROWS * NIMG];

    const int tid = threadIdx.x;
    const int wo  = blockIdx.x * 256 + tid;
    const int ho0 = blockIdx.y * ROWS;

    if (tid < ROWS * NIMG) {
        const int r = tid >> 3;
        const int n = tid & 7;
        ylds[tid] = ytab[(n << 11) + ho0 + r];
    }

    float wx0[NIMG], wx1[NIMG], mxv[NIMG];
    int   ox0[NIMG], ox1[NIMG];
#pragma unroll
    for (int n = 0; n < NIMG; n++) {
        const int4 e = xtab[(n << 11) + wo];
        wx0[n] = __int_as_float(e.x);
        wx1[n] = __int_as_float(e.y);
        ox0[n] = e.z;
        ox1[n] = e.w;
        mxv[n] = wx0[n] + wx1[n];
    }

    __syncthreads();

    for (int r = 0; r < ROWS; r++) {
        const int ho  = ho0 + r;
        const int pix = ho * WO + wo;

        float acc0 = bg[0 * HO * WO + pix];
        float acc1 = bg[1 * HO * WO + pix];
        float acc2 = bg[2 * HO * WO + pix];

#pragma unroll
        for (int n = 0; n < NIMG; n++) {
            const int4 ey = ylds[r * NIMG + n];
            const float wy0 = __int_as_float(ey.x);
            const float wy1 = __int_as_float(ey.y);
            const float m = (wy0 + wy1) * mxv[n];
            if (m > 0.0f) {
                const float* ib = src + n * (CCH * PLANE);
                const int o00 = ey.z + ox0[n];
                const int o01 = ey.z + ox1[n];
                const int o10 = ey.w + ox0[n];
                const int o11 = ey.w + ox1[n];
                const float om = 1.0f - m;
                float s[CCH];
#pragma unroll
                for (int c = 0; c < CCH; c++) {
                    const float* p = ib + c * PLANE;
                    const float v00 = p[o00], v01 = p[o01], v10 = p[o10], v11 = p[o11];
                    s[c] = (v00 * wy0 + v10 * wy1) * wx0[n]
                         + (v01 * wy0 + v11 * wy1) * wx1[n];
                }
                acc0 = acc0 * om + s[0] * m;
                acc1 = acc1 * om + s[1] * m;
                acc2 = acc2 * om + s[2] * m;
            }
        }

        out[0 * HO * WO + pix] = acc0;
        out[1 * HO * WO + pix] = acc1;
        out[2 * HO * WO + pix] = acc2;
    }
}

extern "C" void kernel_launch(void* const* d_in, const int* in_sizes, int n_in,
                              void* d_out, int out_size, void* d_ws, size_t ws_size,
                              hipStream_t stream) {
    const float* src  = (const float*)d_in[0];   // [8,3,512,512]
    const float* bg   = (const float*)d_in[1];   // [1,3,2048,2048]
    const float* coor = (const float*)d_in[2];   // [8,4]
    float* out = (float*)d_out;                  // [1,3,2048,2048]

    const size_t tab_bytes  = (size_t)2 * NIMG * 2048 * sizeof(int4);   // 512 KB
    const size_t srcI_bytes = (size_t)NIMG * PLANE * sizeof(float4);    // 33.5 MB

    if (ws_size >= tab_bytes + srcI_bytes) {
        int4*   xtab = (int4*)d_ws;
        int4*   ytab = xtab + NIMG * 2048;
        float4* srcI = (float4*)((char*)d_ws + tab_bytes);

        hipLaunchKernelGGL(diffcomp_tables, dim3(128), dim3(256), 0, stream,
                           coor, xtab, ytab);
        hipLaunchKernelGGL(diffcomp_interleave, dim3(NIMG * PLANE / 256), dim3(256),
                           0, stream, src, srcI);
        dim3 grid(WO / 256, HO / ROWS);
        hipLaunchKernelGGL(diffcomp_main3, grid, dim3(256), 0, stream,
                           srcI, bg, xtab, ytab, out);
    } else {
        // Table-only fallback (fits in 512 KB)
        int4* xtab = (int4*)d_ws;
        int4* ytab = xtab + NIMG * 2048;
        hipLaunchKernelGGL(diffcomp_tables, dim3(128), dim3(256), 0, stream,
                           coor, xtab, ytab);
        dim3 grid(WO / 256, HO / ROWS);
        hipLaunchKernelGGL(diffcomp_main2, grid, dim3(256), 0, stream,
                           src, bg, xtab, ytab, out);
    }
}